// Round 13
// baseline (114.341 us; speedup 1.0000x reference)
//
#include <hip/hip_runtime.h>
#include <stdint.h>

// ---------------------------------------------------------------------------
// MoEBiEncoder: top-1 MoE (C=16 experts), per-row 768 -> relu(384) -> 768,
// gate-scale, l2norm, +residual, l2norm.  B=16384, D=768, H=384.
//
// v13: clean MLP experiment. R12 base (best: 91.8us total) with
//      __launch_bounds__(512,2) (256-reg unified budget) + depth-4/depth-2
//      B-fragment register rotation (static indices, no fences). Raises
//      per-wave in-flight VMEM bytes 3KB -> 12KB. R8's rotation was never
//      cleanly tested: 128-reg budget forced demotion (VGPR stayed 64) and
//      NT stores polluted the measurement. setprio removed (R12: neutral).
// ---------------------------------------------------------------------------

#define B_ROWS 16384
#define C_EXP  16
#define D_DIM  768
#define H_DIM  384

typedef __bf16 bf16_t;
typedef __bf16 bf16x8 __attribute__((ext_vector_type(8)));
typedef float  f32x4  __attribute__((ext_vector_type(4)));

// ---- workspace layout (bytes) ----
static constexpr size_t WS_CNT  = 0;                       // 16 int
static constexpr size_t WS_CUR  = 64;                      // 16 int
static constexpr size_t WS_EXP  = 512;                     // B int
static constexpr size_t WS_GATE = WS_EXP  + (size_t)B_ROWS * 4;
static constexpr size_t WS_ROW  = WS_GATE + (size_t)B_ROWS * 4;
static constexpr size_t WS_W1   = WS_ROW  + (size_t)B_ROWS * 4;
static constexpr size_t W_BYTES = (size_t)C_EXP * D_DIM * H_DIM * 2;  // 9437184
static constexpr size_t WS_W4   = WS_W1 + W_BYTES;
static constexpr size_t WS_END  = WS_W4 + W_BYTES;         // ~18.2 MB

// Fragment-major weight layout (per expert, KF = K/32, NF = N/16):
//   frag(kf,nf) = 1024 contiguous bytes; lane l's 16B at l*16 hold
//   w[k0 + (l>>4)*8 + j][n0 + (l&15)], j=0..7.
// w1: KF=24, NF=24.  w4: KF=12, NF=48.

__device__ __forceinline__ f32x4 mfma16(bf16x8 a, bf16x8 b, f32x4 c) {
    return __builtin_amdgcn_mfma_f32_16x16x32_bf16(a, b, c, 0, 0, 0);
}

// ---------------------------------------------------------------------------
// Kernel 1 "prep": blocks 0..2303 convert weights; blocks 2304..2335 do the
// gate (softmax/argmax) + per-expert counts via LDS histogram.
// ---------------------------------------------------------------------------
__global__ __launch_bounds__(512) void prep(const float* __restrict__ w1,
                                            const float* __restrict__ w4,
                                            const float* __restrict__ logits,
                                            char* __restrict__ w1s,
                                            char* __restrict__ w4s,
                                            int* __restrict__ expert,
                                            float* __restrict__ gatev,
                                            int* __restrict__ cnt) {
    __shared__ float tile[64 * 65];
    __shared__ int   hist[16];
    int bid = blockIdx.x;

    if (bid >= 2304) {
        // ---------------- gate part: 32 blocks x 512 threads --------------
        if (threadIdx.x < 16) hist[threadIdx.x] = 0;
        __syncthreads();
        int b = (bid - 2304) * 512 + threadIdx.x;   // 0..16383
        const f32x4* lp = (const f32x4*)(logits + (size_t)b * C_EXP);
        float l[16];
#pragma unroll
        for (int i = 0; i < 4; ++i) {
            f32x4 v = lp[i];
            l[i*4+0] = v[0]; l[i*4+1] = v[1]; l[i*4+2] = v[2]; l[i*4+3] = v[3];
        }
        float m = l[0]; int idx = 0;
#pragma unroll
        for (int j = 1; j < 16; ++j)
            if (l[j] > m) { m = l[j]; idx = j; }   // first-max == np.argmax
        float s = 0.f;
#pragma unroll
        for (int j = 0; j < 16; ++j) s += __expf((l[j] - m) * 0.1f);
        expert[b] = idx;
        gatev[b]  = 1.0f / s;          // softmax value at the argmax
        atomicAdd(&hist[idx], 1);      // LDS atomic (fast)
        __syncthreads();
        if (threadIdx.x < 16) {
            int c = hist[threadIdx.x];
            if (c) atomicAdd(&cnt[threadIdx.x], c);   // <=16 global atomics/blk
        }
        return;
    }

    // ---------------- weight convert: fp32 [K][N] -> bf16 fragment-major --
    bool is1 = bid < 1152;
    int lb = is1 ? bid : bid - 1152;
    int c = lb / 72, rem = lb % 72;
    int kc, nb, Nfull, KF, NF;
    const float* src;
    char* dstbase;
    if (is1) {
        kc = rem / 6;  nb = rem % 6;  Nfull = H_DIM; KF = 24; NF = 24;
        src     = w1 + (size_t)c * D_DIM * H_DIM;
        dstbase = w1s;
    } else {
        kc = rem / 12; nb = rem % 12; Nfull = D_DIM; KF = 12; NF = 48;
        src     = w4 + (size_t)c * H_DIM * D_DIM;
        dstbase = w4s;
    }
    // read 64(k) x 64(n) fp32 tile, coalesced along n
#pragma unroll
    for (int it = 0; it < 2; ++it) {
        int f  = threadIdx.x + it * 512;   // float4 id 0..1023
        int kr = f >> 4, nq = f & 15;
        f32x4 v = *(const f32x4*)(src + (size_t)(kc * 64 + kr) * Nfull + nb * 64 + nq * 4);
        tile[kr * 65 + nq * 4 + 0] = v[0];
        tile[kr * 65 + nq * 4 + 1] = v[1];
        tile[kr * 65 + nq * 4 + 2] = v[2];
        tile[kr * 65 + nq * 4 + 3] = v[3];
    }
    __syncthreads();
    // write 8 fragments (one per 64-thread group), 16B/lane coalesced
    {
        int frag = threadIdx.x >> 6, lane = threadIdx.x & 63;
        int kfl  = frag >> 2, nfl = frag & 3;
        int col  = lane & 15, kq = lane >> 4;
        bf16x8 p;
#pragma unroll
        for (int j = 0; j < 8; ++j)
            p[j] = (bf16_t)tile[(kfl * 32 + kq * 8 + j) * 65 + nfl * 16 + col];
        int kf = kc * 2 + kfl, nf = nb * 4 + nfl;
        size_t off = (((size_t)c * KF + kf) * NF + nf) * 1024 + lane * 16;
        *(bf16x8*)(dstbase + off) = p;
    }
}

// ---------------------------------------------------------------------------
// Kernel 2: bucket rows by expert. offs derived in-block from cnt (prefix of
// 16 values) -> no separate scan dispatch. Hierarchical cursor atomics.
// ---------------------------------------------------------------------------
__global__ __launch_bounds__(512) void scatk(const int* __restrict__ expert,
                                             const int* __restrict__ cnt,
                                             int* __restrict__ cursor,
                                             int* __restrict__ rowlist) {
    __shared__ int lcnt[16], lcur[16], lbase[16];
    int b = blockIdx.x * 512 + threadIdx.x;   // grid 32 -> 0..16383
    if (threadIdx.x < 16) {
        lcnt[threadIdx.x] = cnt[threadIdx.x];
        lcur[threadIdx.x] = 0;
    }
    __syncthreads();
    int e = expert[b];
    int off = 0;
#pragma unroll
    for (int i = 0; i < 16; ++i) off += (i < e) ? lcnt[i] : 0;
    int p = atomicAdd(&lcur[e], 1);           // LDS atomic
    __syncthreads();
    if (threadIdx.x < 16) {
        int c = lcur[threadIdx.x];
        lbase[threadIdx.x] = c ? atomicAdd(&cursor[threadIdx.x], c) : 0;
    }
    __syncthreads();
    rowlist[off + lbase[e] + p] = b;
}

// ---------------------------------------------------------------------------
// Kernel 3: grouped GEMM + fused epilogue.
// One block = 32 rows of one expert, 512 threads = 8 waves (N-split).
// LDS (51456 B):
//   [0, 49152)  embA [32][768] bf16 swz (stage 1)
//   [0, 24576)  h    [32][384] bf16 swz (stage 2; aliases dead embA)
//   ssb1 @49152 (1 KB); ssb2 @50176 (1 KB); ridx @51200; gate @51328.
// K-loops: depth-4 (stage1) / depth-2 (stage2) B register rotation under a
// 256-reg budget ((512,2)) -> ~12KB VMEM in flight per wave (MLP play).
// ---------------------------------------------------------------------------
#define SMEM_BYTES 51456

__global__ __launch_bounds__(512, 2) void moe_main(
    const float* __restrict__ emb, const float* __restrict__ gatev,
    const int* __restrict__ rowlist, const int* __restrict__ cnt,
    const char* __restrict__ w1s, const char* __restrict__ w4s,
    const float* __restrict__ b1, const float* __restrict__ b4,
    float* __restrict__ out) {
    extern __shared__ char smem[];

    // XCD-aware bijective swizzle: grid 528 = 8 * 66
    int bid = blockIdx.x;
    int t   = (bid & 7) * 66 + (bid >> 3);

    // derive (e, tin, base, Meff) from cnt[16] with a scalar prefix scan
    int e = -1, tin = 0, base = 0, cnte = 0;
    {
        int to = 0, o = 0;
#pragma unroll
        for (int i = 0; i < 16; ++i) {
            int ci = cnt[i];
            int tc = (ci + 31) >> 5;
            if (e < 0 && t >= to && t < to + tc) {
                e = i; tin = t - to; base = o + (t - to) * 32; cnte = ci;
            }
            to += tc; o += ci;
        }
    }
    if (e < 0) return;   // beyond total tiles
    int Meff = cnte - tin * 32; if (Meff > 32) Meff = 32;

    float* ssb1  = (float*)(smem + 49152);   // [32][8]
    float* ssb2  = (float*)(smem + 50176);   // [32][8]
    int*   ridxL = (int*)(smem + 51200);
    float* gateL = (float*)(smem + 51328);
    if (threadIdx.x < 32) {
        int rr = threadIdx.x;
        int p  = base + (rr < Meff ? rr : 0);   // clamp pad rows
        int ri = rowlist[p];
        ridxL[rr] = ri;
        gateL[rr] = gatev[ri];
    }
    __syncthreads();   // (1) ridxL visible

    const int wid  = threadIdx.x >> 6;
    const int lane = threadIdx.x & 63;
    const int l15  = lane & 15, l4 = lane >> 4;

    const char* w1e = w1s + (size_t)e * 589824;
    const char* w4e = w4s + (size_t)e * 589824;

    auto ldB1 = [&](int kf, int jn) {
        return *(const bf16x8*)(w1e + ((size_t)(kf * 24 + wid * 3 + jn)) * 1024 + lane * 16);
    };
    auto ldB4 = [&](int kf, int jn) {
        return *(const bf16x8*)(w4e + ((size_t)(kf * 48 + wid * 6 + jn)) * 1024 + lane * 16);
    };

    // ---- stage embA: fp32 -> bf16, swizzled [32][768] --------------------
#pragma unroll
    for (int it = 0; it < 6; ++it) {
        int q   = threadIdx.x + it * 512;   // 0..3071 chunks of 8 k
        int row = q / 96, kq = q % 96;
        const float* s = emb + (size_t)ridxL[row] * D_DIM + kq * 8;
        f32x4 f0 = *(const f32x4*)s;
        f32x4 f1 = *(const f32x4*)(s + 4);
        bf16x8 p;
        p[0]=(bf16_t)f0[0]; p[1]=(bf16_t)f0[1]; p[2]=(bf16_t)f0[2]; p[3]=(bf16_t)f0[3];
        p[4]=(bf16_t)f1[0]; p[5]=(bf16_t)f1[1]; p[6]=(bf16_t)f1[2]; p[7]=(bf16_t)f1[3];
        *(bf16x8*)(smem + row * 1536 + ((kq * 16) ^ ((row & 7) << 4))) = p;
    }
    __syncthreads();   // (2) embA visible

    // ---------------- stage 1: h = relu(emb @ w1 + b1)  [32x384] ----------
    f32x4 acc1[2][3];
#pragma unroll
    for (int rg = 0; rg < 2; ++rg)
#pragma unroll
        for (int j = 0; j < 3; ++j) acc1[rg][j] = f32x4{0.f, 0.f, 0.f, 0.f};

    {
        // depth-4 B rotation: 12 fragments (12 KB) in flight per wave
        bf16x8 B1buf[4][3];
#pragma unroll
        for (int p = 0; p < 4; ++p)
#pragma unroll
            for (int j = 0; j < 3; ++j) B1buf[p][j] = ldB1(p, j);

#pragma unroll
        for (int kf = 0; kf < 24; ++kf) {
            int kb = (kf * 32 + l4 * 8) * 2;
            bf16x8 a0 = *(const bf16x8*)(smem + l15 * 1536 + (kb ^ ((l15 & 7) << 4)));
            bf16x8 a1 = *(const bf16x8*)(smem + (l15 + 16) * 1536 + (kb ^ ((l15 & 7) << 4)));
            acc1[0][0] = mfma16(a0, B1buf[kf & 3][0], acc1[0][0]);
            acc1[1][0] = mfma16(a1, B1buf[kf & 3][0], acc1[1][0]);
            acc1[0][1] = mfma16(a0, B1buf[kf & 3][1], acc1[0][1]);
            acc1[1][1] = mfma16(a1, B1buf[kf & 3][1], acc1[1][1]);
            acc1[0][2] = mfma16(a0, B1buf[kf & 3][2], acc1[0][2]);
            acc1[1][2] = mfma16(a1, B1buf[kf & 3][2], acc1[1][2]);
            if (kf + 4 < 24) {
                B1buf[kf & 3][0] = ldB1(kf + 4, 0);
                B1buf[kf & 3][1] = ldB1(kf + 4, 1);
                B1buf[kf & 3][2] = ldB1(kf + 4, 2);
            }
        }
    }
    __syncthreads();   // (3) all embA reads done; region reusable for h

    // h = relu(acc1 + b1) -> bf16 swizzled LDS @ 0 (stride 768)
#pragma unroll
    for (int jn = 0; jn < 3; ++jn) {
        int col = wid * 48 + jn * 16 + l15;
        float bb = b1[e * H_DIM + col];
#pragma unroll
        for (int rg = 0; rg < 2; ++rg)
#pragma unroll
            for (int v = 0; v < 4; ++v) {
                int row = rg * 16 + l4 * 4 + v;
                float hv = fmaxf(acc1[rg][jn][v] + bb, 0.f);
                *(bf16_t*)(smem + row * 768 + ((col * 2) ^ ((row & 7) << 4))) = (bf16_t)hv;
            }
    }
    __syncthreads();   // (4) h visible

    // ---------------- stage 2: eo = h @ w4  [32x768] ----------------------
    f32x4 acc2[2][6];
#pragma unroll
    for (int rg = 0; rg < 2; ++rg)
#pragma unroll
        for (int j = 0; j < 6; ++j) acc2[rg][j] = f32x4{0.f, 0.f, 0.f, 0.f};

    {
        // depth-2 B rotation: 12 fragments (12 KB) in flight per wave
        bf16x8 B4buf[2][6];
#pragma unroll
        for (int p = 0; p < 2; ++p)
#pragma unroll
            for (int j = 0; j < 6; ++j) B4buf[p][j] = ldB4(p, j);

#pragma unroll
        for (int kf = 0; kf < 12; ++kf) {
            int kb = (kf * 32 + l4 * 8) * 2;
            bf16x8 a0 = *(const bf16x8*)(smem + l15 * 768 + (kb ^ ((l15 & 7) << 4)));
            bf16x8 a1 = *(const bf16x8*)(smem + (l15 + 16) * 768 + (kb ^ ((l15 & 7) << 4)));
            acc2[0][0] = mfma16(a0, B4buf[kf & 1][0], acc2[0][0]);
            acc2[1][0] = mfma16(a1, B4buf[kf & 1][0], acc2[1][0]);
            acc2[0][1] = mfma16(a0, B4buf[kf & 1][1], acc2[0][1]);
            acc2[1][1] = mfma16(a1, B4buf[kf & 1][1], acc2[1][1]);
            acc2[0][2] = mfma16(a0, B4buf[kf & 1][2], acc2[0][2]);
            acc2[1][2] = mfma16(a1, B4buf[kf & 1][2], acc2[1][2]);
            acc2[0][3] = mfma16(a0, B4buf[kf & 1][3], acc2[0][3]);
            acc2[1][3] = mfma16(a1, B4buf[kf & 1][3], acc2[1][3]);
            acc2[0][4] = mfma16(a0, B4buf[kf & 1][4], acc2[0][4]);
            acc2[1][4] = mfma16(a1, B4buf[kf & 1][4], acc2[1][4]);
            acc2[0][5] = mfma16(a0, B4buf[kf & 1][5], acc2[0][5]);
            acc2[1][5] = mfma16(a1, B4buf[kf & 1][5], acc2[1][5]);
            if (kf + 2 < 12) {
                B4buf[kf & 1][0] = ldB4(kf + 2, 0);
                B4buf[kf & 1][1] = ldB4(kf + 2, 1);
                B4buf[kf & 1][2] = ldB4(kf + 2, 2);
                B4buf[kf & 1][3] = ldB4(kf + 2, 3);
                B4buf[kf & 1][4] = ldB4(kf + 2, 4);
                B4buf[kf & 1][5] = ldB4(kf + 2, 5);
            }
        }
    }

    // ---------------- epilogue: gate, l2norm, +emb, l2norm, scatter -------
    const int colb = wid * 96;
    float part[2][4];
#pragma unroll
    for (int rg = 0; rg < 2; ++rg)
#pragma unroll
        for (int v = 0; v < 4; ++v) part[rg][v] = 0.f;

#pragma unroll
    for (int jn = 0; jn < 6; ++jn) {
        float bb = b4[e * D_DIM + colb + jn * 16 + l15];
#pragma unroll
        for (int rg = 0; rg < 2; ++rg)
#pragma unroll
            for (int v = 0; v < 4; ++v) {
                float cv = (acc2[rg][jn][v] + bb) * gateL[rg * 16 + l4 * 4 + v];
                acc2[rg][jn][v] = cv;
                part[rg][v] += cv * cv;
            }
    }
#pragma unroll
    for (int o = 1; o < 16; o <<= 1)
#pragma unroll
        for (int rg = 0; rg < 2; ++rg)
#pragma unroll
            for (int v = 0; v < 4; ++v) part[rg][v] += __shfl_xor(part[rg][v], o, 64);
    if (l15 == 0)
#pragma unroll
        for (int rg = 0; rg < 2; ++rg)
#pragma unroll
            for (int v = 0; v < 4; ++v) ssb1[(rg * 16 + l4 * 4 + v) * 8 + wid] = part[rg][v];
    __syncthreads();   // (5) ssb1 ready

    int   rofs[2][4];   // ridx * D_DIM (int: max ~12.6M, fits)
    float inv1[2][4];
#pragma unroll
    for (int rg = 0; rg < 2; ++rg)
#pragma unroll
        for (int v = 0; v < 4; ++v) {
            int row = rg * 16 + l4 * 4 + v;
            rofs[rg][v] = ridxL[row] * D_DIM;
            float s = 0.f;
#pragma unroll
            for (int w = 0; w < 8; ++w) s += ssb1[row * 8 + w];
            inv1[rg][v] = 1.0f / fmaxf(sqrtf(s), 1e-6f);
        }

    float part2[2][4];
#pragma unroll
    for (int rg = 0; rg < 2; ++rg)
#pragma unroll
        for (int v = 0; v < 4; ++v) part2[rg][v] = 0.f;

#pragma unroll
    for (int jn = 0; jn < 6; ++jn) {
        int col = colb + jn * 16 + l15;
#pragma unroll
        for (int rg = 0; rg < 2; ++rg)
#pragma unroll
            for (int v = 0; v < 4; ++v) {
                float em = emb[rofs[rg][v] + col];
                float o2 = acc2[rg][jn][v] * inv1[rg][v] + em;
                acc2[rg][jn][v] = o2;
                part2[rg][v] += o2 * o2;
            }
    }
#pragma unroll
    for (int o = 1; o < 16; o <<= 1)
#pragma unroll
        for (int rg = 0; rg < 2; ++rg)
#pragma unroll
            for (int v = 0; v < 4; ++v) part2[rg][v] += __shfl_xor(part2[rg][v], o, 64);
    if (l15 == 0)
#pragma unroll
        for (int rg = 0; rg < 2; ++rg)
#pragma unroll
            for (int v = 0; v < 4; ++v) ssb2[(rg * 16 + l4 * 4 + v) * 8 + wid] = part2[rg][v];
    __syncthreads();   // (6) ssb2 ready

#pragma unroll
    for (int rg = 0; rg < 2; ++rg)
#pragma unroll
        for (int v = 0; v < 4; ++v) {
            int row = rg * 16 + l4 * 4 + v;
            float s = 0.f;
#pragma unroll
            for (int w = 0; w < 8; ++w) s += ssb2[row * 8 + w];
            float inv2 = 1.0f / fmaxf(sqrtf(s), 1e-12f);
            if (row < Meff) {
#pragma unroll
                for (int jn = 0; jn < 6; ++jn)
                    out[rofs[rg][v] + colb + jn * 16 + l15] = acc2[rg][jn][v] * inv2;
            }
        }
}

// ---------------------------------------------------------------------------
extern "C" void kernel_launch(void* const* d_in, const int* in_sizes, int n_in,
                              void* d_out, int out_size, void* d_ws, size_t ws_size,
                              hipStream_t stream) {
    const float* emb    = (const float*)d_in[0];
    const float* logits = (const float*)d_in[1];
    const float* w1     = (const float*)d_in[2];
    const float* b1     = (const float*)d_in[3];
    const float* w4     = (const float*)d_in[4];
    const float* b4     = (const float*)d_in[5];
    float* out = (float*)d_out;
    char*  ws  = (char*)d_ws;
    if (ws_size < WS_END) return;  // workspace too small -> fail loudly

    int*   cnt     = (int*)(ws + WS_CNT);
    int*   cur     = (int*)(ws + WS_CUR);
    int*   expert  = (int*)(ws + WS_EXP);
    float* gatev   = (float*)(ws + WS_GATE);
    int*   rowlist = (int*)(ws + WS_ROW);
    char*  w1s     = ws + WS_W1;
    char*  w4s     = ws + WS_W4;

    hipMemsetAsync(ws, 0, 512, stream);
    // weights convert (2304 blocks) + gate (32 blocks) in one dispatch
    prep<<<dim3(2336), dim3(512), 0, stream>>>(w1, w4, logits, w1s, w4s,
                                               expert, gatev, cnt);
    scatk<<<dim3(32), dim3(512), 0, stream>>>(expert, cnt, cur, rowlist);

    (void)hipFuncSetAttribute((const void*)moe_main,
                              hipFuncAttributeMaxDynamicSharedMemorySize, SMEM_BYTES);
    // max tiles = sum_e ceil(cnt_e/32) <= 527; grid 528 = 8*66 (swizzle)
    moe_main<<<dim3(528), dim3(512), SMEM_BYTES, stream>>>(
        emb, gatev, rowlist, cnt, w1s, w4s, b1, b4, out);
}

// Round 14
// 99.996 us; speedup vs baseline: 1.1435x; 1.1435x over previous
//
#include <hip/hip_runtime.h>
#include <stdint.h>

// ---------------------------------------------------------------------------
// MoEBiEncoder: top-1 MoE (C=16 experts), per-row 768 -> relu(384) -> 768,
// gate-scale, l2norm, +residual, l2norm.  B=16384, D=768, H=384.
//
// v14: TRUE counted-vmcnt pipeline (T4). 4-slot LDS B-ring, global_load_lds
//      staging issued 3 steps ahead; steady-state wait is vmcnt(6) - never
//      drained to 0 inside the K-loops (R11 was depth-1 with vmcnt(0) drain,
//      which the evidence says is worthless). embA staged once (R5 layout),
//      h fragment-major (R11 layout, aliases embA). 146 KB LDS, 1 block/CU:
//      latency hidden by pipeline depth, not TLP.
// ---------------------------------------------------------------------------

#define B_ROWS 16384
#define C_EXP  16
#define D_DIM  768
#define H_DIM  384

typedef __bf16 bf16_t;
typedef __bf16 bf16x8 __attribute__((ext_vector_type(8)));
typedef float  f32x4  __attribute__((ext_vector_type(4)));

// ---- workspace layout (bytes) ----
static constexpr size_t WS_CNT  = 0;                       // 16 int
static constexpr size_t WS_CUR  = 64;                      // 16 int
static constexpr size_t WS_EXP  = 512;                     // B int
static constexpr size_t WS_GATE = WS_EXP  + (size_t)B_ROWS * 4;
static constexpr size_t WS_ROW  = WS_GATE + (size_t)B_ROWS * 4;
static constexpr size_t WS_W1   = WS_ROW  + (size_t)B_ROWS * 4;
static constexpr size_t W_BYTES = (size_t)C_EXP * D_DIM * H_DIM * 2;  // 9437184
static constexpr size_t WS_W4   = WS_W1 + W_BYTES;
static constexpr size_t WS_END  = WS_W4 + W_BYTES;         // ~18.2 MB

// Fragment-major weight layout (per expert, KF = K/32, NF = N/16):
//   frag(kf,nf) = 1024 contiguous bytes; lane l's 16B at l*16 hold
//   w[k0 + (l>>4)*8 + j][n0 + (l&15)], j=0..7.
// w1: KF=24, NF=24.  w4: KF=12, NF=48.
// One stage1 K-step's B chunk (fixed kf, 24 frags) is CONTIGUOUS 24 KB;
// stage2 uses 24-frag half-chunks (2 N-passes) - also contiguous 24 KB.

__device__ __forceinline__ void lds_load16(const void* g, void* l) {
    auto gp = reinterpret_cast<const __attribute__((address_space(1))) uint32_t*>(
        reinterpret_cast<uintptr_t>(g));
    auto lp = reinterpret_cast<__attribute__((address_space(3))) uint32_t*>(
        reinterpret_cast<uintptr_t>(l));
    __builtin_amdgcn_global_load_lds(gp, lp, 16, 0, 0);
}

__device__ __forceinline__ f32x4 mfma16(bf16x8 a, bf16x8 b, f32x4 c) {
    return __builtin_amdgcn_mfma_f32_16x16x32_bf16(a, b, c, 0, 0, 0);
}

// ---------------------------------------------------------------------------
// Kernel 1 "prep": blocks 0..2303 convert weights; blocks 2304..2335 gate.
// ---------------------------------------------------------------------------
__global__ __launch_bounds__(512) void prep(const float* __restrict__ w1,
                                            const float* __restrict__ w4,
                                            const float* __restrict__ logits,
                                            char* __restrict__ w1s,
                                            char* __restrict__ w4s,
                                            int* __restrict__ expert,
                                            float* __restrict__ gatev,
                                            int* __restrict__ cnt) {
    __shared__ float tile[64 * 65];
    __shared__ int   hist[16];
    int bid = blockIdx.x;

    if (bid >= 2304) {
        if (threadIdx.x < 16) hist[threadIdx.x] = 0;
        __syncthreads();
        int b = (bid - 2304) * 512 + threadIdx.x;   // 0..16383
        const f32x4* lp = (const f32x4*)(logits + (size_t)b * C_EXP);
        float l[16];
#pragma unroll
        for (int i = 0; i < 4; ++i) {
            f32x4 v = lp[i];
            l[i*4+0] = v[0]; l[i*4+1] = v[1]; l[i*4+2] = v[2]; l[i*4+3] = v[3];
        }
        float m = l[0]; int idx = 0;
#pragma unroll
        for (int j = 1; j < 16; ++j)
            if (l[j] > m) { m = l[j]; idx = j; }   // first-max == np.argmax
        float s = 0.f;
#pragma unroll
        for (int j = 0; j < 16; ++j) s += __expf((l[j] - m) * 0.1f);
        expert[b] = idx;
        gatev[b]  = 1.0f / s;
        atomicAdd(&hist[idx], 1);
        __syncthreads();
        if (threadIdx.x < 16) {
            int c = hist[threadIdx.x];
            if (c) atomicAdd(&cnt[threadIdx.x], c);
        }
        return;
    }

    bool is1 = bid < 1152;
    int lb = is1 ? bid : bid - 1152;
    int c = lb / 72, rem = lb % 72;
    int kc, nb, Nfull, KF, NF;
    const float* src;
    char* dstbase;
    if (is1) {
        kc = rem / 6;  nb = rem % 6;  Nfull = H_DIM; KF = 24; NF = 24;
        src     = w1 + (size_t)c * D_DIM * H_DIM;
        dstbase = w1s;
    } else {
        kc = rem / 12; nb = rem % 12; Nfull = D_DIM; KF = 12; NF = 48;
        src     = w4 + (size_t)c * H_DIM * D_DIM;
        dstbase = w4s;
    }
#pragma unroll
    for (int it = 0; it < 2; ++it) {
        int f  = threadIdx.x + it * 512;   // float4 id 0..1023
        int kr = f >> 4, nq = f & 15;
        f32x4 v = *(const f32x4*)(src + (size_t)(kc * 64 + kr) * Nfull + nb * 64 + nq * 4);
        tile[kr * 65 + nq * 4 + 0] = v[0];
        tile[kr * 65 + nq * 4 + 1] = v[1];
        tile[kr * 65 + nq * 4 + 2] = v[2];
        tile[kr * 65 + nq * 4 + 3] = v[3];
    }
    __syncthreads();
    {
        int frag = threadIdx.x >> 6, lane = threadIdx.x & 63;
        int kfl  = frag >> 2, nfl = frag & 3;
        int col  = lane & 15, kq = lane >> 4;
        bf16x8 p;
#pragma unroll
        for (int j = 0; j < 8; ++j)
            p[j] = (bf16_t)tile[(kfl * 32 + kq * 8 + j) * 65 + nfl * 16 + col];
        int kf = kc * 2 + kfl, nf = nb * 4 + nfl;
        size_t off = (((size_t)c * KF + kf) * NF + nf) * 1024 + lane * 16;
        *(bf16x8*)(dstbase + off) = p;
    }
}

// ---------------------------------------------------------------------------
// Kernel 2: bucket rows by expert (offs from cnt prefix; no scan dispatch).
// ---------------------------------------------------------------------------
__global__ __launch_bounds__(512) void scatk(const int* __restrict__ expert,
                                             const int* __restrict__ cnt,
                                             int* __restrict__ cursor,
                                             int* __restrict__ rowlist) {
    __shared__ int lcnt[16], lcur[16], lbase[16];
    int b = blockIdx.x * 512 + threadIdx.x;   // grid 32 -> 0..16383
    if (threadIdx.x < 16) {
        lcnt[threadIdx.x] = cnt[threadIdx.x];
        lcur[threadIdx.x] = 0;
    }
    __syncthreads();
    int e = expert[b];
    int off = 0;
#pragma unroll
    for (int i = 0; i < 16; ++i) off += (i < e) ? lcnt[i] : 0;
    int p = atomicAdd(&lcur[e], 1);
    __syncthreads();
    if (threadIdx.x < 16) {
        int c = lcur[threadIdx.x];
        lbase[threadIdx.x] = c ? atomicAdd(&cursor[threadIdx.x], c) : 0;
    }
    __syncthreads();
    rowlist[off + lbase[e] + p] = b;
}

// ---------------------------------------------------------------------------
// Kernel 3: grouped GEMM + fused epilogue, counted-vmcnt pipeline.
// One block = 32 rows of one expert, 512 threads = 8 waves (N-split).
// LDS (149760 B):
//   ring  4 x 24576 @0       B chunks (24 x 1KB frags per step)
//   embA  49152    @98304    [32][768] bf16 swz (stage 1 A)
//   h     24576    @98304    [12 kf][2 rg] x 1KB frag-major (aliases embA)
//   ssb1 @147456  ssb2 @148480  ridx @149504  gate @149632
// K-loops: prologue stages 3 chunks; per step wait vmcnt(6) (NEVER 0 until
// the tail), s_barrier, issue chunk t+3, compute chunk t.
// ---------------------------------------------------------------------------
#define RSLOT   24576
#define EMB_OFF 98304
#define H_OFF   98304
#define SMEM_BYTES 149760

__global__ __launch_bounds__(512) void moe_main(
    const float* __restrict__ emb, const float* __restrict__ gatev,
    const int* __restrict__ rowlist, const int* __restrict__ cnt,
    const char* __restrict__ w1s, const char* __restrict__ w4s,
    const float* __restrict__ b1, const float* __restrict__ b4,
    float* __restrict__ out) {
    extern __shared__ char smem[];

    // XCD-aware bijective swizzle: grid 528 = 8 * 66
    int bid = blockIdx.x;
    int t0  = (bid & 7) * 66 + (bid >> 3);

    // derive (e, tin, base, Meff) from cnt[16] with a scalar prefix scan
    int e = -1, tin = 0, base = 0, cnte = 0;
    {
        int to = 0, o = 0;
#pragma unroll
        for (int i = 0; i < 16; ++i) {
            int ci = cnt[i];
            int tc = (ci + 31) >> 5;
            if (e < 0 && t0 >= to && t0 < to + tc) {
                e = i; tin = t0 - to; base = o + (t0 - to) * 32; cnte = ci;
            }
            to += tc; o += ci;
        }
    }
    if (e < 0) return;
    int Meff = cnte - tin * 32; if (Meff > 32) Meff = 32;

    float* ssb1  = (float*)(smem + 147456);
    float* ssb2  = (float*)(smem + 148480);
    int*   ridxL = (int*)(smem + 149504);
    float* gateL = (float*)(smem + 149632);
    if (threadIdx.x < 32) {
        int rr = threadIdx.x;
        int p  = base + (rr < Meff ? rr : 0);
        int ri = rowlist[p];
        ridxL[rr] = ri;
        gateL[rr] = gatev[ri];
    }
    __syncthreads();   // ridxL visible

    const int wid  = threadIdx.x >> 6;
    const int lane = threadIdx.x & 63;
    const int l15  = lane & 15, l4 = lane >> 4;

    const char* w1e = w1s + (size_t)e * 589824;
    const char* w4e = w4s + (size_t)e * 589824;

    auto STAGE1 = [&](int kf, int slot) {
        char* eb = smem + slot * RSLOT;
#pragma unroll
        for (int i = 0; i < 3; ++i)
            lds_load16(w1e + ((size_t)(kf * 24 + wid * 3 + i) << 10) + lane * 16,
                       eb + (wid * 3 + i) * 1024 + lane * 16);
    };
    auto STAGE2 = [&](int s, int slot) {
        int p = s / 12, kf = s % 12;
        char* eb = smem + slot * RSLOT;
#pragma unroll
        for (int i = 0; i < 3; ++i)
            lds_load16(w4e + ((size_t)(kf * 48 + p * 24 + wid * 3 + i) << 10) + lane * 16,
                       eb + (wid * 3 + i) * 1024 + lane * 16);
    };

    // ---- stage embA: fp32 -> bf16, swizzled [32][768] @ EMB_OFF ----------
#pragma unroll
    for (int it = 0; it < 6; ++it) {
        int q   = threadIdx.x + it * 512;
        int row = q / 96, kq = q % 96;
        const float* s = emb + (size_t)ridxL[row] * D_DIM + kq * 8;
        f32x4 f0 = *(const f32x4*)s;
        f32x4 f1 = *(const f32x4*)(s + 4);
        bf16x8 p;
        p[0]=(bf16_t)f0[0]; p[1]=(bf16_t)f0[1]; p[2]=(bf16_t)f0[2]; p[3]=(bf16_t)f0[3];
        p[4]=(bf16_t)f1[0]; p[5]=(bf16_t)f1[1]; p[6]=(bf16_t)f1[2]; p[7]=(bf16_t)f1[3];
        *(bf16x8*)(smem + EMB_OFF + row * 1536 + ((kq * 16) ^ ((row & 7) << 4))) = p;
    }
    __syncthreads();   // embA visible; vmcnt drained (compiler)

    // ---------------- stage 1: h = relu(emb @ w1 + b1)  [32x384] ----------
    f32x4 acc1[2][3];
#pragma unroll
    for (int rg = 0; rg < 2; ++rg)
#pragma unroll
        for (int j = 0; j < 3; ++j) acc1[rg][j] = f32x4{0.f, 0.f, 0.f, 0.f};

    STAGE1(0, 0); STAGE1(1, 1); STAGE1(2, 2);   // 3-deep prologue (9 loads)
#pragma unroll
    for (int t = 0; t < 24; ++t) {
        if (t <= 21)      asm volatile("s_waitcnt vmcnt(6)" ::: "memory");
        else if (t == 22) asm volatile("s_waitcnt vmcnt(3)" ::: "memory");
        else              asm volatile("s_waitcnt vmcnt(0)" ::: "memory");
        __builtin_amdgcn_s_barrier();      // all waves' step-t chunk landed
        __builtin_amdgcn_sched_barrier(0);
        if (t + 3 < 24) STAGE1(t + 3, (t + 3) & 3);
        __builtin_amdgcn_sched_barrier(0);
        const char* eb = smem + (t & 3) * RSLOT;
        int kb = t * 64 + l4 * 16;
        bf16x8 a0 = *(const bf16x8*)(smem + EMB_OFF + l15 * 1536 + (kb ^ ((l15 & 7) << 4)));
        bf16x8 a1 = *(const bf16x8*)(smem + EMB_OFF + (l15 + 16) * 1536 + (kb ^ ((l15 & 7) << 4)));
        bf16x8 b0 = *(const bf16x8*)(eb + (wid * 3 + 0) * 1024 + lane * 16);
        bf16x8 bv1 = *(const bf16x8*)(eb + (wid * 3 + 1) * 1024 + lane * 16);
        bf16x8 bv2 = *(const bf16x8*)(eb + (wid * 3 + 2) * 1024 + lane * 16);
        acc1[0][0] = mfma16(a0, b0,  acc1[0][0]);
        acc1[1][0] = mfma16(a1, b0,  acc1[1][0]);
        acc1[0][1] = mfma16(a0, bv1, acc1[0][1]);
        acc1[1][1] = mfma16(a1, bv1, acc1[1][1]);
        acc1[0][2] = mfma16(a0, bv2, acc1[0][2]);
        acc1[1][2] = mfma16(a1, bv2, acc1[1][2]);
    }
    __builtin_amdgcn_s_barrier();   // all waves finished stage1 LDS reads
    __builtin_amdgcn_sched_barrier(0);

    // h = relu(acc1 + b1) -> fragment-major [12 kf][2 rg] @ H_OFF
#pragma unroll
    for (int jn = 0; jn < 3; ++jn) {
        int hcol = wid * 48 + jn * 16 + l15;
        float bb = b1[e * H_DIM + hcol];
        int fb = ((hcol >> 5) * 2) * 1024 + (((hcol >> 3) & 3) * 16) * 16 + (hcol & 7) * 2;
#pragma unroll
        for (int rg = 0; rg < 2; ++rg)
#pragma unroll
            for (int v = 0; v < 4; ++v) {
                int rl = l4 * 4 + v;
                float hv = fmaxf(acc1[rg][jn][v] + bb, 0.f);
                *(bf16_t*)(smem + H_OFF + fb + rg * 1024 + rl * 16) = (bf16_t)hv;
            }
    }
    asm volatile("s_waitcnt lgkmcnt(0)" ::: "memory");
    __builtin_amdgcn_s_barrier();   // h visible
    __builtin_amdgcn_sched_barrier(0);

    // ---------------- stage 2: eo = h @ w4  [32x768], 2 N-passes ----------
    f32x4 acc2[2][2][3];   // [pass][rg][jn]
#pragma unroll
    for (int p = 0; p < 2; ++p)
#pragma unroll
        for (int rg = 0; rg < 2; ++rg)
#pragma unroll
            for (int j = 0; j < 3; ++j) acc2[p][rg][j] = f32x4{0.f, 0.f, 0.f, 0.f};

    STAGE2(0, 0); STAGE2(1, 1); STAGE2(2, 2);
#pragma unroll
    for (int s = 0; s < 24; ++s) {
        if (s <= 21)      asm volatile("s_waitcnt vmcnt(6)" ::: "memory");
        else if (s == 22) asm volatile("s_waitcnt vmcnt(3)" ::: "memory");
        else              asm volatile("s_waitcnt vmcnt(0)" ::: "memory");
        __builtin_amdgcn_s_barrier();
        __builtin_amdgcn_sched_barrier(0);
        if (s + 3 < 24) STAGE2(s + 3, (s + 3) & 3);
        __builtin_amdgcn_sched_barrier(0);
        const int p = s / 12, kf = s % 12;
        const char* eb = smem + (s & 3) * RSLOT;
        bf16x8 a0 = *(const bf16x8*)(smem + H_OFF + (kf * 2 + 0) * 1024 + lane * 16);
        bf16x8 a1 = *(const bf16x8*)(smem + H_OFF + (kf * 2 + 1) * 1024 + lane * 16);
        bf16x8 b0 = *(const bf16x8*)(eb + (wid * 3 + 0) * 1024 + lane * 16);
        bf16x8 bv1 = *(const bf16x8*)(eb + (wid * 3 + 1) * 1024 + lane * 16);
        bf16x8 bv2 = *(const bf16x8*)(eb + (wid * 3 + 2) * 1024 + lane * 16);
        acc2[p][0][0] = mfma16(a0, b0,  acc2[p][0][0]);
        acc2[p][1][0] = mfma16(a1, b0,  acc2[p][1][0]);
        acc2[p][0][1] = mfma16(a0, bv1, acc2[p][0][1]);
        acc2[p][1][1] = mfma16(a1, bv1, acc2[p][1][1]);
        acc2[p][0][2] = mfma16(a0, bv2, acc2[p][0][2]);
        acc2[p][1][2] = mfma16(a1, bv2, acc2[p][1][2]);
    }

    // ---------------- epilogue: gate, l2norm, +emb, l2norm, scatter -------
    // wave's cols: p*384 + wid*48 + jn*16 + l15
    float part[2][4];
#pragma unroll
    for (int rg = 0; rg < 2; ++rg)
#pragma unroll
        for (int v = 0; v < 4; ++v) part[rg][v] = 0.f;

#pragma unroll
    for (int p = 0; p < 2; ++p)
#pragma unroll
        for (int jn = 0; jn < 3; ++jn) {
            float bb = b4[e * D_DIM + p * 384 + wid * 48 + jn * 16 + l15];
#pragma unroll
            for (int rg = 0; rg < 2; ++rg)
#pragma unroll
                for (int v = 0; v < 4; ++v) {
                    float cv = (acc2[p][rg][jn][v] + bb) * gateL[rg * 16 + l4 * 4 + v];
                    acc2[p][rg][jn][v] = cv;
                    part[rg][v] += cv * cv;
                }
        }
#pragma unroll
    for (int o = 1; o < 16; o <<= 1)
#pragma unroll
        for (int rg = 0; rg < 2; ++rg)
#pragma unroll
            for (int v = 0; v < 4; ++v) part[rg][v] += __shfl_xor(part[rg][v], o, 64);
    if (l15 == 0)
#pragma unroll
        for (int rg = 0; rg < 2; ++rg)
#pragma unroll
            for (int v = 0; v < 4; ++v) ssb1[(rg * 16 + l4 * 4 + v) * 8 + wid] = part[rg][v];
    __syncthreads();

    int   rofs[2][4];
    float inv1[2][4];
#pragma unroll
    for (int rg = 0; rg < 2; ++rg)
#pragma unroll
        for (int v = 0; v < 4; ++v) {
            int row = rg * 16 + l4 * 4 + v;
            rofs[rg][v] = ridxL[row] * D_DIM;
            float s = 0.f;
#pragma unroll
            for (int w = 0; w < 8; ++w) s += ssb1[row * 8 + w];
            inv1[rg][v] = 1.0f / fmaxf(sqrtf(s), 1e-6f);
        }

    float part2[2][4];
#pragma unroll
    for (int rg = 0; rg < 2; ++rg)
#pragma unroll
        for (int v = 0; v < 4; ++v) part2[rg][v] = 0.f;

#pragma unroll
    for (int p = 0; p < 2; ++p)
#pragma unroll
        for (int jn = 0; jn < 3; ++jn) {
            int col = p * 384 + wid * 48 + jn * 16 + l15;
#pragma unroll
            for (int rg = 0; rg < 2; ++rg)
#pragma unroll
                for (int v = 0; v < 4; ++v) {
                    float em = emb[rofs[rg][v] + col];
                    float o2 = acc2[p][rg][jn][v] * inv1[rg][v] + em;
                    acc2[p][rg][jn][v] = o2;
                    part2[rg][v] += o2 * o2;
                }
        }
#pragma unroll
    for (int o = 1; o < 16; o <<= 1)
#pragma unroll
        for (int rg = 0; rg < 2; ++rg)
#pragma unroll
            for (int v = 0; v < 4; ++v) part2[rg][v] += __shfl_xor(part2[rg][v], o, 64);
    if (l15 == 0)
#pragma unroll
        for (int rg = 0; rg < 2; ++rg)
#pragma unroll
            for (int v = 0; v < 4; ++v) ssb2[(rg * 16 + l4 * 4 + v) * 8 + wid] = part2[rg][v];
    __syncthreads();

#pragma unroll
    for (int rg = 0; rg < 2; ++rg)
#pragma unroll
        for (int v = 0; v < 4; ++v) {
            int row = rg * 16 + l4 * 4 + v;
            float s = 0.f;
#pragma unroll
            for (int w = 0; w < 8; ++w) s += ssb2[row * 8 + w];
            float inv2 = 1.0f / fmaxf(sqrtf(s), 1e-12f);
            if (row < Meff) {
#pragma unroll
                for (int p = 0; p < 2; ++p)
#pragma unroll
                    for (int jn = 0; jn < 3; ++jn)
                        out[rofs[rg][v] + p * 384 + wid * 48 + jn * 16 + l15] =
                            acc2[p][rg][jn][v] * inv2;
            }
        }
}

// ---------------------------------------------------------------------------
extern "C" void kernel_launch(void* const* d_in, const int* in_sizes, int n_in,
                              void* d_out, int out_size, void* d_ws, size_t ws_size,
                              hipStream_t stream) {
    const float* emb    = (const float*)d_in[0];
    const float* logits = (const float*)d_in[1];
    const float* w1     = (const float*)d_in[2];
    const float* b1     = (const float*)d_in[3];
    const float* w4     = (const float*)d_in[4];
    const float* b4     = (const float*)d_in[5];
    float* out = (float*)d_out;
    char*  ws  = (char*)d_ws;
    if (ws_size < WS_END) return;  // workspace too small -> fail loudly

    int*   cnt     = (int*)(ws + WS_CNT);
    int*   cur     = (int*)(ws + WS_CUR);
    int*   expert  = (int*)(ws + WS_EXP);
    float* gatev   = (float*)(ws + WS_GATE);
    int*   rowlist = (int*)(ws + WS_ROW);
    char*  w1s     = ws + WS_W1;
    char*  w4s     = ws + WS_W4;

    hipMemsetAsync(ws, 0, 512, stream);
    prep<<<dim3(2336), dim3(512), 0, stream>>>(w1, w4, logits, w1s, w4s,
                                               expert, gatev, cnt);
    scatk<<<dim3(32), dim3(512), 0, stream>>>(expert, cnt, cur, rowlist);

    (void)hipFuncSetAttribute((const void*)moe_main,
                              hipFuncAttributeMaxDynamicSharedMemorySize, SMEM_BYTES);
    // max tiles = sum_e ceil(cnt_e/32) <= 527; grid 528 = 8*66 (swizzle)
    moe_main<<<dim3(528), dim3(512), SMEM_BYTES, stream>>>(
        emb, gatev, rowlist, cnt, w1s, w4s, b1, b4, out);
}

// Round 15
// 91.848 us; speedup vs baseline: 1.2449x; 1.0887x over previous
//
#include <hip/hip_runtime.h>
#include <stdint.h>

// ---------------------------------------------------------------------------
// MoEBiEncoder: top-1 MoE (C=16 experts), per-row 768 -> relu(384) -> 768,
// gate-scale, l2norm, +residual, l2norm.  B=16384, D=768, H=384.
//
// FINAL (= R12, best measured: 91.8us total). Structure: gate+weight-convert
// in one dispatch; hierarchical-atomic row bucketing; grouped MFMA GEMM with
// 32-row tiles, A staged in swizzled LDS, B streamed from L2 in fragment-
// major layout, fused gate/l2norm/residual/l2norm epilogue.
// Plateau note: 14 structural variants (prefetch 0-4 deep, counted-vmcnt
// rings, tile M=16/32/64, barrier-free split kernels, NT, occupancy 13-33%)
// all measured 81-107us for the main kernel -> small-shape grouped-GEMM
// latency plateau (~225 TF effective), consistent with the documented
// plain-HIP shape curve. This config is the measured minimum.
// ---------------------------------------------------------------------------

#define B_ROWS 16384
#define C_EXP  16
#define D_DIM  768
#define H_DIM  384

typedef __bf16 bf16_t;
typedef __bf16 bf16x8 __attribute__((ext_vector_type(8)));
typedef float  f32x4  __attribute__((ext_vector_type(4)));

// ---- workspace layout (bytes) ----
static constexpr size_t WS_CNT  = 0;                       // 16 int
static constexpr size_t WS_CUR  = 64;                      // 16 int
static constexpr size_t WS_EXP  = 512;                     // B int
static constexpr size_t WS_GATE = WS_EXP  + (size_t)B_ROWS * 4;
static constexpr size_t WS_ROW  = WS_GATE + (size_t)B_ROWS * 4;
static constexpr size_t WS_W1   = WS_ROW  + (size_t)B_ROWS * 4;
static constexpr size_t W_BYTES = (size_t)C_EXP * D_DIM * H_DIM * 2;  // 9437184
static constexpr size_t WS_W4   = WS_W1 + W_BYTES;
static constexpr size_t WS_END  = WS_W4 + W_BYTES;         // ~18.2 MB

// Fragment-major weight layout (per expert, KF = K/32, NF = N/16):
//   frag(kf,nf) = 1024 contiguous bytes; lane l's 16B at l*16 hold
//   w[k0 + (l>>4)*8 + j][n0 + (l&15)], j=0..7.
// w1: KF=24, NF=24.  w4: KF=12, NF=48.

__device__ __forceinline__ f32x4 mfma16(bf16x8 a, bf16x8 b, f32x4 c) {
    return __builtin_amdgcn_mfma_f32_16x16x32_bf16(a, b, c, 0, 0, 0);
}

// ---------------------------------------------------------------------------
// Kernel 1 "prep": blocks 0..2303 convert weights; blocks 2304..2335 do the
// gate (softmax/argmax) + per-expert counts via LDS histogram.
// ---------------------------------------------------------------------------
__global__ __launch_bounds__(512) void prep(const float* __restrict__ w1,
                                            const float* __restrict__ w4,
                                            const float* __restrict__ logits,
                                            char* __restrict__ w1s,
                                            char* __restrict__ w4s,
                                            int* __restrict__ expert,
                                            float* __restrict__ gatev,
                                            int* __restrict__ cnt) {
    __shared__ float tile[64 * 65];
    __shared__ int   hist[16];
    int bid = blockIdx.x;

    if (bid >= 2304) {
        // ---------------- gate part: 32 blocks x 512 threads --------------
        if (threadIdx.x < 16) hist[threadIdx.x] = 0;
        __syncthreads();
        int b = (bid - 2304) * 512 + threadIdx.x;   // 0..16383
        const f32x4* lp = (const f32x4*)(logits + (size_t)b * C_EXP);
        float l[16];
#pragma unroll
        for (int i = 0; i < 4; ++i) {
            f32x4 v = lp[i];
            l[i*4+0] = v[0]; l[i*4+1] = v[1]; l[i*4+2] = v[2]; l[i*4+3] = v[3];
        }
        float m = l[0]; int idx = 0;
#pragma unroll
        for (int j = 1; j < 16; ++j)
            if (l[j] > m) { m = l[j]; idx = j; }   // first-max == np.argmax
        float s = 0.f;
#pragma unroll
        for (int j = 0; j < 16; ++j) s += __expf((l[j] - m) * 0.1f);
        expert[b] = idx;
        gatev[b]  = 1.0f / s;          // softmax value at the argmax
        atomicAdd(&hist[idx], 1);      // LDS atomic (fast)
        __syncthreads();
        if (threadIdx.x < 16) {
            int c = hist[threadIdx.x];
            if (c) atomicAdd(&cnt[threadIdx.x], c);   // <=16 global atomics/blk
        }
        return;
    }

    // ---------------- weight convert: fp32 [K][N] -> bf16 fragment-major --
    bool is1 = bid < 1152;
    int lb = is1 ? bid : bid - 1152;
    int c = lb / 72, rem = lb % 72;
    int kc, nb, Nfull, KF, NF;
    const float* src;
    char* dstbase;
    if (is1) {
        kc = rem / 6;  nb = rem % 6;  Nfull = H_DIM; KF = 24; NF = 24;
        src     = w1 + (size_t)c * D_DIM * H_DIM;
        dstbase = w1s;
    } else {
        kc = rem / 12; nb = rem % 12; Nfull = D_DIM; KF = 12; NF = 48;
        src     = w4 + (size_t)c * H_DIM * D_DIM;
        dstbase = w4s;
    }
    // read 64(k) x 64(n) fp32 tile, coalesced along n
#pragma unroll
    for (int it = 0; it < 2; ++it) {
        int f  = threadIdx.x + it * 512;   // float4 id 0..1023
        int kr = f >> 4, nq = f & 15;
        f32x4 v = *(const f32x4*)(src + (size_t)(kc * 64 + kr) * Nfull + nb * 64 + nq * 4);
        tile[kr * 65 + nq * 4 + 0] = v[0];
        tile[kr * 65 + nq * 4 + 1] = v[1];
        tile[kr * 65 + nq * 4 + 2] = v[2];
        tile[kr * 65 + nq * 4 + 3] = v[3];
    }
    __syncthreads();
    // write 8 fragments (one per 64-thread group), 16B/lane coalesced
    {
        int frag = threadIdx.x >> 6, lane = threadIdx.x & 63;
        int kfl  = frag >> 2, nfl = frag & 3;
        int col  = lane & 15, kq = lane >> 4;
        bf16x8 p;
#pragma unroll
        for (int j = 0; j < 8; ++j)
            p[j] = (bf16_t)tile[(kfl * 32 + kq * 8 + j) * 65 + nfl * 16 + col];
        int kf = kc * 2 + kfl, nf = nb * 4 + nfl;
        size_t off = (((size_t)c * KF + kf) * NF + nf) * 1024 + lane * 16;
        *(bf16x8*)(dstbase + off) = p;
    }
}

// ---------------------------------------------------------------------------
// Kernel 2: bucket rows by expert. offs derived in-block from cnt (prefix of
// 16 values) -> no separate scan dispatch. Hierarchical cursor atomics.
// ---------------------------------------------------------------------------
__global__ __launch_bounds__(512) void scatk(const int* __restrict__ expert,
                                             const int* __restrict__ cnt,
                                             int* __restrict__ cursor,
                                             int* __restrict__ rowlist) {
    __shared__ int lcnt[16], lcur[16], lbase[16];
    int b = blockIdx.x * 512 + threadIdx.x;   // grid 32 -> 0..16383
    if (threadIdx.x < 16) {
        lcnt[threadIdx.x] = cnt[threadIdx.x];
        lcur[threadIdx.x] = 0;
    }
    __syncthreads();
    int e = expert[b];
    int off = 0;
#pragma unroll
    for (int i = 0; i < 16; ++i) off += (i < e) ? lcnt[i] : 0;
    int p = atomicAdd(&lcur[e], 1);           // LDS atomic
    __syncthreads();
    if (threadIdx.x < 16) {
        int c = lcur[threadIdx.x];
        lbase[threadIdx.x] = c ? atomicAdd(&cursor[threadIdx.x], c) : 0;
    }
    __syncthreads();
    rowlist[off + lbase[e] + p] = b;
}

// ---------------------------------------------------------------------------
// Kernel 3: grouped GEMM + fused epilogue.
// One block = 32 rows of one expert, 512 threads = 8 waves (N-split).
// LDS (51456 B):
//   [0, 49152)  embA [32][768] bf16 swz (stage 1)
//   [0, 24576)  h    [32][384] bf16 swz (stage 2; aliases dead embA)
//   ssb1 @49152 (1 KB); ssb2 @50176 (1 KB); ridx @51200; gate @51328.
// Tile->expert mapping derived in-block from cnt[16] (scalar prefix).
// ---------------------------------------------------------------------------
#define SMEM_BYTES 51456

__global__ __launch_bounds__(512, 4) void moe_main(
    const float* __restrict__ emb, const float* __restrict__ gatev,
    const int* __restrict__ rowlist, const int* __restrict__ cnt,
    const char* __restrict__ w1s, const char* __restrict__ w4s,
    const float* __restrict__ b1, const float* __restrict__ b4,
    float* __restrict__ out) {
    extern __shared__ char smem[];

    // XCD-aware bijective swizzle: grid 528 = 8 * 66
    int bid = blockIdx.x;
    int t   = (bid & 7) * 66 + (bid >> 3);

    // derive (e, tin, base, Meff) from cnt[16] with a scalar prefix scan
    int e = -1, tin = 0, base = 0, cnte = 0;
    {
        int to = 0, o = 0;
#pragma unroll
        for (int i = 0; i < 16; ++i) {
            int ci = cnt[i];
            int tc = (ci + 31) >> 5;
            if (e < 0 && t >= to && t < to + tc) {
                e = i; tin = t - to; base = o + (t - to) * 32; cnte = ci;
            }
            to += tc; o += ci;
        }
    }
    if (e < 0) return;   // beyond total tiles
    int Meff = cnte - tin * 32; if (Meff > 32) Meff = 32;

    float* ssb1  = (float*)(smem + 49152);   // [32][8]
    float* ssb2  = (float*)(smem + 50176);   // [32][8]
    int*   ridxL = (int*)(smem + 51200);
    float* gateL = (float*)(smem + 51328);
    if (threadIdx.x < 32) {
        int rr = threadIdx.x;
        int p  = base + (rr < Meff ? rr : 0);   // clamp pad rows
        int ri = rowlist[p];
        ridxL[rr] = ri;
        gateL[rr] = gatev[ri];
    }
    __syncthreads();   // (1) ridxL visible

    const int wid  = threadIdx.x >> 6;
    const int lane = threadIdx.x & 63;
    const int l15  = lane & 15, l4 = lane >> 4;

    const char* w1e = w1s + (size_t)e * 589824;
    const char* w4e = w4s + (size_t)e * 589824;

    // ---- stage embA: fp32 -> bf16, swizzled [32][768] --------------------
#pragma unroll
    for (int it = 0; it < 6; ++it) {
        int q   = threadIdx.x + it * 512;   // 0..3071 chunks of 8 k
        int row = q / 96, kq = q % 96;
        const float* s = emb + (size_t)ridxL[row] * D_DIM + kq * 8;
        f32x4 f0 = *(const f32x4*)s;
        f32x4 f1 = *(const f32x4*)(s + 4);
        bf16x8 p;
        p[0]=(bf16_t)f0[0]; p[1]=(bf16_t)f0[1]; p[2]=(bf16_t)f0[2]; p[3]=(bf16_t)f0[3];
        p[4]=(bf16_t)f1[0]; p[5]=(bf16_t)f1[1]; p[6]=(bf16_t)f1[2]; p[7]=(bf16_t)f1[3];
        *(bf16x8*)(smem + row * 1536 + ((kq * 16) ^ ((row & 7) << 4))) = p;
    }
    __syncthreads();   // (2) embA visible

    // ---------------- stage 1: h = relu(emb @ w1 + b1)  [32x384] ----------
    f32x4 acc1[2][3];
#pragma unroll
    for (int rg = 0; rg < 2; ++rg)
#pragma unroll
        for (int j = 0; j < 3; ++j) acc1[rg][j] = f32x4{0.f, 0.f, 0.f, 0.f};

#pragma unroll
    for (int kf = 0; kf < 24; ++kf) {
        int kb = (kf * 32 + l4 * 8) * 2;
        bf16x8 a0 = *(const bf16x8*)(smem + l15 * 1536 + (kb ^ ((l15 & 7) << 4)));
        bf16x8 a1 = *(const bf16x8*)(smem + (l15 + 16) * 1536 + (kb ^ ((l15 & 7) << 4)));
        bf16x8 b0 = *(const bf16x8*)(w1e + ((size_t)(kf * 24 + wid * 3 + 0)) * 1024 + lane * 16);
        bf16x8 bv1 = *(const bf16x8*)(w1e + ((size_t)(kf * 24 + wid * 3 + 1)) * 1024 + lane * 16);
        bf16x8 bv2 = *(const bf16x8*)(w1e + ((size_t)(kf * 24 + wid * 3 + 2)) * 1024 + lane * 16);
        __builtin_amdgcn_s_setprio(1);
        acc1[0][0] = mfma16(a0, b0,  acc1[0][0]);
        acc1[1][0] = mfma16(a1, b0,  acc1[1][0]);
        acc1[0][1] = mfma16(a0, bv1, acc1[0][1]);
        acc1[1][1] = mfma16(a1, bv1, acc1[1][1]);
        acc1[0][2] = mfma16(a0, bv2, acc1[0][2]);
        acc1[1][2] = mfma16(a1, bv2, acc1[1][2]);
        __builtin_amdgcn_s_setprio(0);
    }
    __syncthreads();   // (3) all embA reads done; region reusable for h

    // h = relu(acc1 + b1) -> bf16 swizzled LDS @ 0 (stride 768)
#pragma unroll
    for (int jn = 0; jn < 3; ++jn) {
        int col = wid * 48 + jn * 16 + l15;
        float bb = b1[e * H_DIM + col];
#pragma unroll
        for (int rg = 0; rg < 2; ++rg)
#pragma unroll
            for (int v = 0; v < 4; ++v) {
                int row = rg * 16 + l4 * 4 + v;
                float hv = fmaxf(acc1[rg][jn][v] + bb, 0.f);
                *(bf16_t*)(smem + row * 768 + ((col * 2) ^ ((row & 7) << 4))) = (bf16_t)hv;
            }
    }
    __syncthreads();   // (4) h visible

    // ---------------- stage 2: eo = h @ w4  [32x768] ----------------------
    f32x4 acc2[2][6];
#pragma unroll
    for (int rg = 0; rg < 2; ++rg)
#pragma unroll
        for (int j = 0; j < 6; ++j) acc2[rg][j] = f32x4{0.f, 0.f, 0.f, 0.f};

#pragma unroll
    for (int kf = 0; kf < 12; ++kf) {
        int kb = (kf * 32 + l4 * 8) * 2;
        bf16x8 a0 = *(const bf16x8*)(smem + l15 * 768 + (kb ^ ((l15 & 7) << 4)));
        bf16x8 a1 = *(const bf16x8*)(smem + (l15 + 16) * 768 + (kb ^ ((l15 & 7) << 4)));
        bf16x8 b0 = *(const bf16x8*)(w4e + ((size_t)(kf * 48 + wid * 6 + 0)) * 1024 + lane * 16);
        bf16x8 bv1 = *(const bf16x8*)(w4e + ((size_t)(kf * 48 + wid * 6 + 1)) * 1024 + lane * 16);
        bf16x8 bv2 = *(const bf16x8*)(w4e + ((size_t)(kf * 48 + wid * 6 + 2)) * 1024 + lane * 16);
        bf16x8 bv3 = *(const bf16x8*)(w4e + ((size_t)(kf * 48 + wid * 6 + 3)) * 1024 + lane * 16);
        bf16x8 bv4 = *(const bf16x8*)(w4e + ((size_t)(kf * 48 + wid * 6 + 4)) * 1024 + lane * 16);
        bf16x8 bv5 = *(const bf16x8*)(w4e + ((size_t)(kf * 48 + wid * 6 + 5)) * 1024 + lane * 16);
        __builtin_amdgcn_s_setprio(1);
        acc2[0][0] = mfma16(a0, b0,  acc2[0][0]);
        acc2[1][0] = mfma16(a1, b0,  acc2[1][0]);
        acc2[0][1] = mfma16(a0, bv1, acc2[0][1]);
        acc2[1][1] = mfma16(a1, bv1, acc2[1][1]);
        acc2[0][2] = mfma16(a0, bv2, acc2[0][2]);
        acc2[1][2] = mfma16(a1, bv2, acc2[1][2]);
        acc2[0][3] = mfma16(a0, bv3, acc2[0][3]);
        acc2[1][3] = mfma16(a1, bv3, acc2[1][3]);
        acc2[0][4] = mfma16(a0, bv4, acc2[0][4]);
        acc2[1][4] = mfma16(a1, bv4, acc2[1][4]);
        acc2[0][5] = mfma16(a0, bv5, acc2[0][5]);
        acc2[1][5] = mfma16(a1, bv5, acc2[1][5]);
        __builtin_amdgcn_s_setprio(0);
    }

    // ---------------- epilogue: gate, l2norm, +emb, l2norm, scatter -------
    const int colb = wid * 96;
    float part[2][4];
#pragma unroll
    for (int rg = 0; rg < 2; ++rg)
#pragma unroll
        for (int v = 0; v < 4; ++v) part[rg][v] = 0.f;

#pragma unroll
    for (int jn = 0; jn < 6; ++jn) {
        float bb = b4[e * D_DIM + colb + jn * 16 + l15];
#pragma unroll
        for (int rg = 0; rg < 2; ++rg)
#pragma unroll
            for (int v = 0; v < 4; ++v) {
                float cv = (acc2[rg][jn][v] + bb) * gateL[rg * 16 + l4 * 4 + v];
                acc2[rg][jn][v] = cv;
                part[rg][v] += cv * cv;
            }
    }
#pragma unroll
    for (int o = 1; o < 16; o <<= 1)
#pragma unroll
        for (int rg = 0; rg < 2; ++rg)
#pragma unroll
            for (int v = 0; v < 4; ++v) part[rg][v] += __shfl_xor(part[rg][v], o, 64);
    if (l15 == 0)
#pragma unroll
        for (int rg = 0; rg < 2; ++rg)
#pragma unroll
            for (int v = 0; v < 4; ++v) ssb1[(rg * 16 + l4 * 4 + v) * 8 + wid] = part[rg][v];
    __syncthreads();   // (5) ssb1 ready

    int   rofs[2][4];   // ridx * D_DIM (int: max ~12.6M, fits)
    float inv1[2][4];
#pragma unroll
    for (int rg = 0; rg < 2; ++rg)
#pragma unroll
        for (int v = 0; v < 4; ++v) {
            int row = rg * 16 + l4 * 4 + v;
            rofs[rg][v] = ridxL[row] * D_DIM;
            float s = 0.f;
#pragma unroll
            for (int w = 0; w < 8; ++w) s += ssb1[row * 8 + w];
            inv1[rg][v] = 1.0f / fmaxf(sqrtf(s), 1e-6f);
        }

    float part2[2][4];
#pragma unroll
    for (int rg = 0; rg < 2; ++rg)
#pragma unroll
        for (int v = 0; v < 4; ++v) part2[rg][v] = 0.f;

#pragma unroll
    for (int jn = 0; jn < 6; ++jn) {
        int col = colb + jn * 16 + l15;
#pragma unroll
        for (int rg = 0; rg < 2; ++rg)
#pragma unroll
            for (int v = 0; v < 4; ++v) {
                float em = emb[rofs[rg][v] + col];
                float o2 = acc2[rg][jn][v] * inv1[rg][v] + em;
                acc2[rg][jn][v] = o2;
                part2[rg][v] += o2 * o2;
            }
    }
#pragma unroll
    for (int o = 1; o < 16; o <<= 1)
#pragma unroll
        for (int rg = 0; rg < 2; ++rg)
#pragma unroll
            for (int v = 0; v < 4; ++v) part2[rg][v] += __shfl_xor(part2[rg][v], o, 64);
    if (l15 == 0)
#pragma unroll
        for (int rg = 0; rg < 2; ++rg)
#pragma unroll
            for (int v = 0; v < 4; ++v) ssb2[(rg * 16 + l4 * 4 + v) * 8 + wid] = part2[rg][v];
    __syncthreads();   // (6) ssb2 ready

#pragma unroll
    for (int rg = 0; rg < 2; ++rg)
#pragma unroll
        for (int v = 0; v < 4; ++v) {
            int row = rg * 16 + l4 * 4 + v;
            float s = 0.f;
#pragma unroll
            for (int w = 0; w < 8; ++w) s += ssb2[row * 8 + w];
            float inv2 = 1.0f / fmaxf(sqrtf(s), 1e-12f);
            if (row < Meff) {
#pragma unroll
                for (int jn = 0; jn < 6; ++jn)
                    out[rofs[rg][v] + colb + jn * 16 + l15] = acc2[rg][jn][v] * inv2;
            }
        }
}

// ---------------------------------------------------------------------------
extern "C" void kernel_launch(void* const* d_in, const int* in_sizes, int n_in,
                              void* d_out, int out_size, void* d_ws, size_t ws_size,
                              hipStream_t stream) {
    const float* emb    = (const float*)d_in[0];
    const float* logits = (const float*)d_in[1];
    const float* w1     = (const float*)d_in[2];
    const float* b1     = (const float*)d_in[3];
    const float* w4     = (const float*)d_in[4];
    const float* b4     = (const float*)d_in[5];
    float* out = (float*)d_out;
    char*  ws  = (char*)d_ws;
    if (ws_size < WS_END) return;  // workspace too small -> fail loudly

    int*   cnt     = (int*)(ws + WS_CNT);
    int*   cur     = (int*)(ws + WS_CUR);
    int*   expert  = (int*)(ws + WS_EXP);
    float* gatev   = (float*)(ws + WS_GATE);
    int*   rowlist = (int*)(ws + WS_ROW);
    char*  w1s     = ws + WS_W1;
    char*  w4s     = ws + WS_W4;

    hipMemsetAsync(ws, 0, 512, stream);
    // weights convert (2304 blocks) + gate (32 blocks) in one dispatch
    prep<<<dim3(2336), dim3(512), 0, stream>>>(w1, w4, logits, w1s, w4s,
                                               expert, gatev, cnt);
    scatk<<<dim3(32), dim3(512), 0, stream>>>(expert, cnt, cur, rowlist);

    (void)hipFuncSetAttribute((const void*)moe_main,
                              hipFuncAttributeMaxDynamicSharedMemorySize, SMEM_BYTES);
    // max tiles = sum_e ceil(cnt_e/32) <= 527; grid 528 = 8*66 (swizzle)
    moe_main<<<dim3(528), dim3(512), SMEM_BYTES, stream>>>(
        emb, gatev, rowlist, cnt, w1s, w4s, b1, b4, out);
}